// Round 3
// baseline (824.283 us; speedup 1.0000x reference)
//
#include <hip/hip_runtime.h>
#include <stdint.h>

#define NB 32
#define CC 256
#define HH 56
#define WW 56
#define PP (HH*WW)          // 3136
#define NPIX (NB*PP)        // 100352
#define W32 8               // 256 channels / 32 bits
#define KEPS 1e-5f

// ---------------- BN stats: per-(n,c) plane partial sums -> atomics ----------------
__global__ void k_stats(const float* __restrict__ x, float* __restrict__ ssum, float* __restrict__ ssq) {
    int plane = blockIdx.x;               // n*CC + c
    int c = plane & (CC - 1);
    const float* xp = x + (size_t)plane * PP;
    float s = 0.f, q = 0.f;
    for (int i = threadIdx.x; i < PP; i += blockDim.x) {
        float v = xp[i]; s += v; q = fmaf(v, v, q);
    }
#pragma unroll
    for (int off = 32; off; off >>= 1) { s += __shfl_down(s, off); q += __shfl_down(q, off); }
    __shared__ float ls[4], lq[4];
    int wv = threadIdx.x >> 6, ln = threadIdx.x & 63;
    if (ln == 0) { ls[wv] = s; lq[wv] = q; }
    __syncthreads();
    if (threadIdx.x == 0) {
        float S = 0.f, Q = 0.f;
        for (int w = 0; w < 4; ++w) { S += ls[w]; Q += lq[w]; }
        atomicAdd(&ssum[c], S); atomicAdd(&ssq[c], Q);
    }
}

// ---- BN2 stats from int16 conv sums: val = relu(alpha1[o]*k1[pix]*acc) ------------
__global__ void k_stats2(const short* __restrict__ ci, const float* __restrict__ alpha1,
                         const float* __restrict__ k1, float* __restrict__ ssum, float* __restrict__ ssq) {
    int plane = blockIdx.x;               // n*CC + o
    int o = plane & (CC - 1);
    int n = plane >> 8;
    const short* cp = ci + (size_t)plane * PP;
    const float* kp = k1 + (size_t)n * PP;
    float al = alpha1[o];
    float s = 0.f, q = 0.f;
    for (int i = threadIdx.x; i < PP; i += blockDim.x) {
        float v = fmaxf(al * kp[i] * (float)cp[i], 0.f);
        s += v; q = fmaf(v, v, q);
    }
#pragma unroll
    for (int off = 32; off; off >>= 1) { s += __shfl_down(s, off); q += __shfl_down(q, off); }
    __shared__ float ls[4], lq[4];
    int wv = threadIdx.x >> 6, ln = threadIdx.x & 63;
    if (ln == 0) { ls[wv] = s; lq[wv] = q; }
    __syncthreads();
    if (threadIdx.x == 0) {
        float S = 0.f, Q = 0.f;
        for (int w = 0; w < 4; ++w) { S += ls[w]; Q += lq[w]; }
        atomicAdd(&ssum[o], S); atomicAdd(&ssq[o], Q);
    }
}

// ---------------- finalize BN: scale = g/sqrt(var+eps), bias = beta - m*scale ------
__global__ void k_fin(const float* __restrict__ ssum, const float* __restrict__ ssq,
                      const float* __restrict__ gamma, const float* __restrict__ beta,
                      float* __restrict__ scale, float* __restrict__ bias) {
    int c = threadIdx.x;
    float m   = ssum[c] * (1.0f / NPIX);
    float var = fmaf(-m, m, ssq[c] * (1.0f / NPIX));
    float s   = gamma[c] / sqrtf(var + KEPS);
    scale[c] = s;
    bias[c]  = fmaf(-m, s, beta[c]);
}

// ---------------- weight prep: sign-pack + alpha + border-adjust table -------------
// Layout: wb[(t*CC + o)*W32 + wd]  (tap-major) so the conv's per-tap o-stream
// is contiguous for scalar loads.
// adj[o][type] = 256*nvalid(type) + 2 * sum_{t in invalid(type)} popc(wbits[o][t])
__global__ void k_wprep(const float* __restrict__ w1, const float* __restrict__ w2,
                        uint32_t* __restrict__ wb1, uint32_t* __restrict__ wb2,
                        float* __restrict__ al1, float* __restrict__ al2,
                        int* __restrict__ adj1, int* __restrict__ adj2) {
    int o2 = blockIdx.x;                  // 0..511
    const float* w = (o2 < CC) ? w1 : w2;
    uint32_t* wb   = (o2 < CC) ? wb1 : wb2;
    float* al      = (o2 < CC) ? al1 : al2;
    int* adj       = (o2 < CC) ? adj1 : adj2;
    int o = o2 & (CC - 1);
    int lane = threadIdx.x;               // 64
    float asum = 0.f;
    int pt[9] = {0,0,0,0,0,0,0,0,0};      // popcount of sign bits per tap (all lanes)
    for (int cg = 0; cg < 4; ++cg) {
        int c = cg * 64 + lane;
        const float* wp = w + ((size_t)o * CC + c) * 9;
        for (int t = 0; t < 9; ++t) {
            float wv = wp[t];
            asum += fabsf(wv);
            unsigned long long m = __ballot(wv >= 0.0f);
            pt[t] += __popcll(m);
            if (lane == 0) {
                wb[(t * CC + o) * W32 + cg * 2]     = (uint32_t)m;
                wb[(t * CC + o) * W32 + cg * 2 + 1] = (uint32_t)(m >> 32);
            }
        }
    }
#pragma unroll
    for (int off = 32; off; off >>= 1) asum += __shfl_down(asum, off);
    if (lane == 0) al[o] = asum * (1.0f / 2304.0f);
    if (lane < 9) {
        const unsigned vm[3] = {0u, 0x007u, 0x1C0u};   // top rows / bottom rows
        const unsigned hm[3] = {0u, 0x049u, 0x124u};   // left cols / right cols
        unsigned mask = vm[lane / 3] | hm[lane % 3];
        int nv = 9 - __popc(mask);
        int wsum = 0;
#pragma unroll
        for (int t = 0; t < 9; ++t) if ((mask >> t) & 1) wsum += pt[t];
        adj[o * 16 + lane] = 256 * nv + 2 * wsum;
    }
}

// ---------------- BN1 apply + sign pack + channel-mean a1 --------------------------
__global__ void k_bn1pack(const float* __restrict__ x, const float* __restrict__ scale,
                          const float* __restrict__ bias, uint32_t* __restrict__ xbits,
                          float* __restrict__ a) {
    int lane = threadIdx.x & 63, wv = threadIdx.x >> 6;
    int n = blockIdx.x / 49;                        // 3136 = 49*64 pixels per image
    int pix = blockIdx.x * 64 + lane;
    int p = pix - n * PP;
    const float* xp = x + (size_t)n * CC * PP + p;
    uint32_t b0 = 0, b1 = 0;
    float asum = 0.f;
#pragma unroll
    for (int i = 0; i < 64; ++i) {
        int c = (wv << 6) + i;
        float v = xp[(size_t)c * PP];
        float bnv = fmaf(v, scale[c], bias[c]);
        asum += bnv;
        uint32_t bit = (bnv >= 0.0f) ? 1u : 0u;
        if (i < 32) b0 |= bit << i; else b1 |= bit << (i - 32);
    }
    ((uint2*)xbits)[(size_t)pix * 4 + wv] = make_uint2(b0, b1);
    __shared__ float lsum[4][64];
    lsum[wv][lane] = asum;
    __syncthreads();
    if (wv == 0)
        a[pix] = (lsum[0][lane] + lsum[1][lane] + lsum[2][lane] + lsum[3][lane]) * (1.0f / CC);
}

// ---------------- BN2 apply (recompute val from int16 conv) + pack + a2 ------------
__global__ void k_bn2pack(const short* __restrict__ ci, const float* __restrict__ alpha1,
                          const float* __restrict__ k1, const float* __restrict__ scale,
                          const float* __restrict__ bias, uint32_t* __restrict__ xbits,
                          float* __restrict__ a) {
    int lane = threadIdx.x & 63, wv = threadIdx.x >> 6;
    int n = blockIdx.x / 49;
    int pix = blockIdx.x * 64 + lane;
    int p = pix - n * PP;
    const short* cp = ci + (size_t)n * CC * PP + p;
    float kv = k1[pix];
    uint32_t b0 = 0, b1 = 0;
    float asum = 0.f;
#pragma unroll
    for (int i = 0; i < 64; ++i) {
        int o = (wv << 6) + i;
        float val = fmaxf(alpha1[o] * kv * (float)cp[(size_t)o * PP], 0.f);
        float bnv = fmaf(val, scale[o], bias[o]);
        asum += bnv;
        uint32_t bit = (bnv >= 0.0f) ? 1u : 0u;
        if (i < 32) b0 |= bit << i; else b1 |= bit << (i - 32);
    }
    ((uint2*)xbits)[(size_t)pix * 4 + wv] = make_uint2(b0, b1);
    __shared__ float lsum[4][64];
    lsum[wv][lane] = asum;
    __syncthreads();
    if (wv == 0)
        a[pix] = (lsum[0][lane] + lsum[1][lane] + lsum[2][lane] + lsum[3][lane]) * (1.0f / CC);
}

// ---------------- 3x3 box filter (zero padded, /9) ---------------------------------
__global__ void k_box(const float* __restrict__ a, float* __restrict__ k) {
    int gid = blockIdx.x * 256 + threadIdx.x;    // NPIX
    int n = gid / PP;
    int p = gid - n * PP;
    int h = p / WW, w = p - (p / WW) * WW;
    const float* ap = a + (size_t)n * PP;
    float s = 0.f;
    for (int dr = -1; dr <= 1; ++dr) {
        int hh = h + dr;
        if (hh < 0 || hh >= HH) continue;
        for (int dc = -1; dc <= 1; ++dc) {
            int ww2 = w + dc;
            if (ww2 < 0 || ww2 >= WW) continue;
            s += ap[hh * WW + ww2];
        }
    }
    k[gid] = s * (1.0f / 9.0f);
}

// ---------------- binary conv core: fully-unrolled taps + 1-deep x prefetch --------
// block: 448 threads = 8 rows x 56 cols of pixels, fixed n, TO=16 output channels.
// Tap loop is FULLY UNROLLED (t compile-time): all 18 ds_read_b128 use one base
// VGPR + immediate offset, all weight s_loads use immediate offsets from one SGPR
// base, and tap t+1's x-words are prefetched before tap t's VALU burst so the
// shared lgkmcnt wait (ds_read + s_load share the counter) has a full tap of
// slack. Live set: P[16] + x cur/next (16) + weights transient + addressing
// ~ 55 regs, inside the 64-reg budget pinned by __launch_bounds__(448, 8).
template<bool FIRST>
__global__ __launch_bounds__(448, 8) void k_conv(
    const uint32_t* __restrict__ xbits, const uint32_t* __restrict__ wbits,
    const int* __restrict__ adj, const float* __restrict__ alpha,
    const float* __restrict__ kmap, short* __restrict__ out_i16,
    const float* __restrict__ ident, float* __restrict__ outf)
{
    constexpr int TH = 8, TO = 16;
    constexpr int LW = 58;                            // 56 + 2 col halo
    __shared__ uint32_t lds_x[(TH + 2) * LW * W32];   // 10*58*8*4 = 18560 B

    int b = blockIdx.x;
    int ob = b & 15, hb = (b >> 4) % 7, n = b / 112;
    int h0 = hb * TH, o0 = ob * TO;
    int tid = threadIdx.x;

    // stage rows h0-1..h0+TH, cols -1..56; zero outside image
    for (int i = tid; i < (TH + 2) * LW * 2; i += 448) {   // uint4 units, 116/row
        int r = i / (LW * 2), j = i - r * (LW * 2);
        int c = j >> 1, half = j & 1;
        int gr = h0 - 1 + r, gc = c - 1;
        uint4 v = make_uint4(0u, 0u, 0u, 0u);
        if (gr >= 0 && gr < HH && gc >= 0 && gc < WW)
            v = ((const uint4*)(xbits + ((size_t)n * PP + (size_t)gr * WW + gc) * W32))[half];
        ((uint4*)lds_x)[i] = v;
    }
    __syncthreads();

    int row = tid / WW, col = tid - (tid / WW) * WW;
    int h = h0 + row;
    int vf = (h == 0) ? 1 : ((h == HH - 1) ? 2 : 0);
    int hf = (col == 0) ? 1 : ((col == WW - 1) ? 2 : 0);
    int type = vf * 3 + hf;
    size_t gp = (size_t)n * PP + (size_t)h * WW + col;
    float kv = FIRST ? 0.f : kmap[gp];
    size_t obase = (size_t)n * CC * PP + (size_t)h * WW + col;

    int P[TO];
#pragma unroll
    for (int o = 0; o < TO; ++o) P[o] = 0;

    // base address for tap (0,0); every tap offset is a compile-time immediate
    const uint32_t* xb0p = &lds_x[(row * LW + col) * W32];

    uint4 xa = *(const uint4*)(xb0p);
    uint4 xb = *(const uint4*)(xb0p + 4);

#pragma unroll
    for (int t = 0; t < 9; ++t) {
        // prefetch next tap's x-words (compile-time immediate offsets)
        uint4 na = xa, nb2 = xb;
        if (t < 8) {
            const int dr = (t + 1) / 3, dc = (t + 1) % 3;
            const int off = (dr * LW + dc) * W32;
            na  = *(const uint4*)(xb0p + off);
            nb2 = *(const uint4*)(xb0p + off + 4);
        }
        // wave-uniform weight stream, immediate offsets from one base
        const uint4* __restrict__ wq = (const uint4*)wbits + ((size_t)t * CC + o0) * 2;
#pragma unroll
        for (int o = 0; o < TO; ++o) {
            uint4 wa = wq[o * 2], wb2 = wq[o * 2 + 1];
            int P0 = P[o];
            P0 += __popc(xa.x ^ wa.x);
            P0 += __popc(xa.y ^ wa.y);
            P0 += __popc(xa.z ^ wa.z);
            P0 += __popc(xa.w ^ wa.w);
            P0 += __popc(xb.x ^ wb2.x);
            P0 += __popc(xb.y ^ wb2.y);
            P0 += __popc(xb.z ^ wb2.z);
            P0 += __popc(xb.w ^ wb2.w);
            P[o] = P0;
        }
        xa = na; xb = nb2;
    }

#pragma unroll
    for (int o = 0; o < TO; ++o) {
        int oo = o0 + o;
        int acc = adj[oo * 16 + type] - 2 * P[o];
        size_t oidx = obase + (size_t)oo * PP;
        if (FIRST) {
            out_i16[oidx] = (short)acc;
        } else {
            float res = alpha[oo] * kv * (float)acc;
            outf[oidx] = fmaxf(res + ident[oidx], 0.f);
        }
    }
}

extern "C" void kernel_launch(void* const* d_in, const int* in_sizes, int n_in,
                              void* d_out, int out_size, void* d_ws, size_t ws_size,
                              hipStream_t stream)
{
    const float* x  = (const float*)d_in[0];
    const float* g1 = (const float*)d_in[1];
    const float* b1 = (const float*)d_in[2];
    const float* w1 = (const float*)d_in[3];
    const float* g2 = (const float*)d_in[4];
    const float* b2 = (const float*)d_in[5];
    const float* w2 = (const float*)d_in[6];
    float* out = (float*)d_out;

    char* ws = (char*)d_ws;
    float* s1sum  = (float*)(ws + 0);
    float* s1sq   = (float*)(ws + 1024);
    float* s2sum  = (float*)(ws + 2048);
    float* s2sq   = (float*)(ws + 3072);
    float* scale1 = (float*)(ws + 4096);
    float* bias1  = (float*)(ws + 5120);
    float* scale2 = (float*)(ws + 6144);
    float* bias2  = (float*)(ws + 7168);
    float* alpha1 = (float*)(ws + 8192);
    float* alpha2 = (float*)(ws + 9216);
    int*   adj1   = (int*)(ws + 10240);                   // 16384 B
    int*   adj2   = (int*)(ws + 26624);                   // 16384 B
    uint32_t* wbits1 = (uint32_t*)(ws + 43008);           // 73728 B
    uint32_t* wbits2 = (uint32_t*)(ws + 116736);          // 73728 B
    float* a1 = (float*)(ws + 190464);                    // 401408 B
    float* k1 = (float*)(ws + 591872);
    float* a2 = (float*)(ws + 993280);
    float* k2 = (float*)(ws + 1394688);
    uint32_t* xbits1 = (uint32_t*)(ws + 1796096);         // 3211264 B
    uint32_t* xbits2 = (uint32_t*)(ws + 5007360);         // 3211264 B
    short* ci = (short*)(ws + 8218624);                   // 51380224 B

    hipMemsetAsync(ws, 0, 4096, stream);                  // zero stat accumulators
    k_wprep<<<2 * CC, 64, 0, stream>>>(w1, w2, wbits1, wbits2, alpha1, alpha2, adj1, adj2);
    k_stats<<<NB * CC, 256, 0, stream>>>(x, s1sum, s1sq);
    k_fin<<<1, 256, 0, stream>>>(s1sum, s1sq, g1, b1, scale1, bias1);
    k_bn1pack<<<NPIX / 64, 256, 0, stream>>>(x, scale1, bias1, xbits1, a1);
    k_box<<<NPIX / 256, 256, 0, stream>>>(a1, k1);
    k_conv<true><<<NB * 7 * 16, 448, 0, stream>>>(xbits1, wbits1, adj1, nullptr, nullptr, ci, nullptr, nullptr);
    k_stats2<<<NB * CC, 256, 0, stream>>>(ci, alpha1, k1, s2sum, s2sq);
    k_fin<<<1, 256, 0, stream>>>(s2sum, s2sq, g2, b2, scale2, bias2);
    k_bn2pack<<<NPIX / 64, 256, 0, stream>>>(ci, alpha1, k1, scale2, bias2, xbits2, a2);
    k_box<<<NPIX / 256, 256, 0, stream>>>(a2, k2);
    k_conv<false><<<NB * 7 * 16, 448, 0, stream>>>(xbits2, wbits2, adj2, alpha2, k2, nullptr, x, out);
}

// Round 4
// 570.184 us; speedup vs baseline: 1.4456x; 1.4456x over previous
//
#include <hip/hip_runtime.h>
#include <stdint.h>

#define NB 32
#define CC 256
#define HH 56
#define WW 56
#define PP (HH*WW)          // 3136
#define NPIX (NB*PP)        // 100352
#define W32 8               // 256 channels / 32 bits
#define KEPS 1e-5f

// ---------------- BN stats: per-(n,c) plane partial sums -> atomics ----------------
__global__ void k_stats(const float* __restrict__ x, float* __restrict__ ssum, float* __restrict__ ssq) {
    int plane = blockIdx.x;               // n*CC + c
    int c = plane & (CC - 1);
    const float* xp = x + (size_t)plane * PP;
    float s = 0.f, q = 0.f;
    for (int i = threadIdx.x; i < PP; i += blockDim.x) {
        float v = xp[i]; s += v; q = fmaf(v, v, q);
    }
#pragma unroll
    for (int off = 32; off; off >>= 1) { s += __shfl_down(s, off); q += __shfl_down(q, off); }
    __shared__ float ls[4], lq[4];
    int wv = threadIdx.x >> 6, ln = threadIdx.x & 63;
    if (ln == 0) { ls[wv] = s; lq[wv] = q; }
    __syncthreads();
    if (threadIdx.x == 0) {
        float S = 0.f, Q = 0.f;
        for (int w = 0; w < 4; ++w) { S += ls[w]; Q += lq[w]; }
        atomicAdd(&ssum[c], S); atomicAdd(&ssq[c], Q);
    }
}

// ---- BN2 stats from int16 conv sums: val = relu(alpha1[o]*k1[pix]*acc) ------------
__global__ void k_stats2(const short* __restrict__ ci, const float* __restrict__ alpha1,
                         const float* __restrict__ k1, float* __restrict__ ssum, float* __restrict__ ssq) {
    int plane = blockIdx.x;               // n*CC + o
    int o = plane & (CC - 1);
    int n = plane >> 8;
    const short* cp = ci + (size_t)plane * PP;
    const float* kp = k1 + (size_t)n * PP;
    float al = alpha1[o];
    float s = 0.f, q = 0.f;
    for (int i = threadIdx.x; i < PP; i += blockDim.x) {
        float v = fmaxf(al * kp[i] * (float)cp[i], 0.f);
        s += v; q = fmaf(v, v, q);
    }
#pragma unroll
    for (int off = 32; off; off >>= 1) { s += __shfl_down(s, off); q += __shfl_down(q, off); }
    __shared__ float ls[4], lq[4];
    int wv = threadIdx.x >> 6, ln = threadIdx.x & 63;
    if (ln == 0) { ls[wv] = s; lq[wv] = q; }
    __syncthreads();
    if (threadIdx.x == 0) {
        float S = 0.f, Q = 0.f;
        for (int w = 0; w < 4; ++w) { S += ls[w]; Q += lq[w]; }
        atomicAdd(&ssum[o], S); atomicAdd(&ssq[o], Q);
    }
}

// ---------------- finalize BN: scale = g/sqrt(var+eps), bias = beta - m*scale ------
__global__ void k_fin(const float* __restrict__ ssum, const float* __restrict__ ssq,
                      const float* __restrict__ gamma, const float* __restrict__ beta,
                      float* __restrict__ scale, float* __restrict__ bias) {
    int c = threadIdx.x;
    float m   = ssum[c] * (1.0f / NPIX);
    float var = fmaf(-m, m, ssq[c] * (1.0f / NPIX));
    float s   = gamma[c] / sqrtf(var + KEPS);
    scale[c] = s;
    bias[c]  = fmaf(-m, s, beta[c]);
}

// ---------------- weight prep: sign-pack + alpha + border-adjust table -------------
// Layout: wb[(t*CC + o)*W32 + wd]  (tap-major) so the conv's per-tap o-stream
// is contiguous for scalar loads.
// adj[o][type] = 256*nvalid(type) + 2 * sum_{t in invalid(type)} popc(wbits[o][t])
__global__ void k_wprep(const float* __restrict__ w1, const float* __restrict__ w2,
                        uint32_t* __restrict__ wb1, uint32_t* __restrict__ wb2,
                        float* __restrict__ al1, float* __restrict__ al2,
                        int* __restrict__ adj1, int* __restrict__ adj2) {
    int o2 = blockIdx.x;                  // 0..511
    const float* w = (o2 < CC) ? w1 : w2;
    uint32_t* wb   = (o2 < CC) ? wb1 : wb2;
    float* al      = (o2 < CC) ? al1 : al2;
    int* adj       = (o2 < CC) ? adj1 : adj2;
    int o = o2 & (CC - 1);
    int lane = threadIdx.x;               // 64
    float asum = 0.f;
    int pt[9] = {0,0,0,0,0,0,0,0,0};      // popcount of sign bits per tap (all lanes)
    for (int cg = 0; cg < 4; ++cg) {
        int c = cg * 64 + lane;
        const float* wp = w + ((size_t)o * CC + c) * 9;
        for (int t = 0; t < 9; ++t) {
            float wv = wp[t];
            asum += fabsf(wv);
            unsigned long long m = __ballot(wv >= 0.0f);
            pt[t] += __popcll(m);
            if (lane == 0) {
                wb[(t * CC + o) * W32 + cg * 2]     = (uint32_t)m;
                wb[(t * CC + o) * W32 + cg * 2 + 1] = (uint32_t)(m >> 32);
            }
        }
    }
#pragma unroll
    for (int off = 32; off; off >>= 1) asum += __shfl_down(asum, off);
    if (lane == 0) al[o] = asum * (1.0f / 2304.0f);
    if (lane < 9) {
        const unsigned vm[3] = {0u, 0x007u, 0x1C0u};   // top rows / bottom rows
        const unsigned hm[3] = {0u, 0x049u, 0x124u};   // left cols / right cols
        unsigned mask = vm[lane / 3] | hm[lane % 3];
        int nv = 9 - __popc(mask);
        int wsum = 0;
#pragma unroll
        for (int t = 0; t < 9; ++t) if ((mask >> t) & 1) wsum += pt[t];
        adj[o * 16 + lane] = 256 * nv + 2 * wsum;
    }
}

// ---------------- BN1 apply + sign pack + channel-mean a1 --------------------------
__global__ void k_bn1pack(const float* __restrict__ x, const float* __restrict__ scale,
                          const float* __restrict__ bias, uint32_t* __restrict__ xbits,
                          float* __restrict__ a) {
    int lane = threadIdx.x & 63, wv = threadIdx.x >> 6;
    int n = blockIdx.x / 49;                        // 3136 = 49*64 pixels per image
    int pix = blockIdx.x * 64 + lane;
    int p = pix - n * PP;
    const float* xp = x + (size_t)n * CC * PP + p;
    uint32_t b0 = 0, b1 = 0;
    float asum = 0.f;
#pragma unroll
    for (int i = 0; i < 64; ++i) {
        int c = (wv << 6) + i;
        float v = xp[(size_t)c * PP];
        float bnv = fmaf(v, scale[c], bias[c]);
        asum += bnv;
        uint32_t bit = (bnv >= 0.0f) ? 1u : 0u;
        if (i < 32) b0 |= bit << i; else b1 |= bit << (i - 32);
    }
    ((uint2*)xbits)[(size_t)pix * 4 + wv] = make_uint2(b0, b1);
    __shared__ float lsum[4][64];
    lsum[wv][lane] = asum;
    __syncthreads();
    if (wv == 0)
        a[pix] = (lsum[0][lane] + lsum[1][lane] + lsum[2][lane] + lsum[3][lane]) * (1.0f / CC);
}

// ---------------- BN2 apply (recompute val from int16 conv) + pack + a2 ------------
__global__ void k_bn2pack(const short* __restrict__ ci, const float* __restrict__ alpha1,
                          const float* __restrict__ k1, const float* __restrict__ scale,
                          const float* __restrict__ bias, uint32_t* __restrict__ xbits,
                          float* __restrict__ a) {
    int lane = threadIdx.x & 63, wv = threadIdx.x >> 6;
    int n = blockIdx.x / 49;
    int pix = blockIdx.x * 64 + lane;
    int p = pix - n * PP;
    const short* cp = ci + (size_t)n * CC * PP + p;
    float kv = k1[pix];
    uint32_t b0 = 0, b1 = 0;
    float asum = 0.f;
#pragma unroll
    for (int i = 0; i < 64; ++i) {
        int o = (wv << 6) + i;
        float val = fmaxf(alpha1[o] * kv * (float)cp[(size_t)o * PP], 0.f);
        float bnv = fmaf(val, scale[o], bias[o]);
        asum += bnv;
        uint32_t bit = (bnv >= 0.0f) ? 1u : 0u;
        if (i < 32) b0 |= bit << i; else b1 |= bit << (i - 32);
    }
    ((uint2*)xbits)[(size_t)pix * 4 + wv] = make_uint2(b0, b1);
    __shared__ float lsum[4][64];
    lsum[wv][lane] = asum;
    __syncthreads();
    if (wv == 0)
        a[pix] = (lsum[0][lane] + lsum[1][lane] + lsum[2][lane] + lsum[3][lane]) * (1.0f / CC);
}

// ---------------- 3x3 box filter (zero padded, /9) ---------------------------------
__global__ void k_box(const float* __restrict__ a, float* __restrict__ k) {
    int gid = blockIdx.x * 256 + threadIdx.x;    // NPIX
    int n = gid / PP;
    int p = gid - n * PP;
    int h = p / WW, w = p - (p / WW) * WW;
    const float* ap = a + (size_t)n * PP;
    float s = 0.f;
    for (int dr = -1; dr <= 1; ++dr) {
        int hh = h + dr;
        if (hh < 0 || hh >= HH) continue;
        for (int dc = -1; dc <= 1; ++dc) {
            int ww2 = w + dc;
            if (ww2 < 0 || ww2 >= WW) continue;
            s += ap[hh * WW + ww2];
        }
    }
    k[gid] = s * (1.0f / 9.0f);
}

// ---------------- binary conv core: tap-major, TO=16, batch-paired pixels ----------
// block: 448 threads = 8 rows x 56 cols, fixed image-PAIR (n0,n0+1), TO=16 outputs.
// Each lane computes the SAME (h,col,o-tile) for two images: one 16-o weight
// stream per tap feeds 512 VALU ops instead of 256 (2x stall amortization).
// Accumulators P[16]+Q[16]=32 (same count R0 ran at 2-block residency).
// __launch_bounds__(448,4) gives the allocator a 128-reg budget -> NO spills
// (R3's SGPR-spill catastrophe came from a tight budget + hoisting pressure).
// Taps stay rolled (R3 lesson: full unroll explodes SGPR pressure).
template<bool FIRST>
__global__ __launch_bounds__(448, 4) void k_conv(
    const uint32_t* __restrict__ xbits, const uint32_t* __restrict__ wbits,
    const int* __restrict__ adj, const float* __restrict__ alpha,
    const float* __restrict__ kmap, short* __restrict__ out_i16,
    const float* __restrict__ ident, float* __restrict__ outf)
{
    constexpr int TH = 8, TO = 16;
    constexpr int LW = 58;                            // 56 + 2 col halo
    constexpr int IMG = (TH + 2) * LW * W32;          // LDS dwords per image tile
    __shared__ uint32_t lds_x[2 * IMG];               // 37120 B

    int b = blockIdx.x;
    int ob = b & 15, hb = (b >> 4) % 7, np = b / 112;
    int n0 = np * 2;
    int h0 = hb * TH, o0 = ob * TO;
    int tid = threadIdx.x;

    // stage rows h0-1..h0+TH, cols -1..56, both images; zero outside image
    for (int i = tid; i < 2 * (TH + 2) * LW * 2; i += 448) {   // uint4 units
        int img = i / ((TH + 2) * LW * 2);
        int j = i - img * ((TH + 2) * LW * 2);
        int r = j / (LW * 2), jj = j - r * (LW * 2);
        int c = jj >> 1, half = jj & 1;
        int gr = h0 - 1 + r, gc = c - 1;
        uint4 v = make_uint4(0u, 0u, 0u, 0u);
        if (gr >= 0 && gr < HH && gc >= 0 && gc < WW)
            v = ((const uint4*)(xbits + ((size_t)(n0 + img) * PP + (size_t)gr * WW + gc) * W32))[half];
        ((uint4*)lds_x)[i] = v;
    }
    __syncthreads();

    int row = tid / WW, col = tid - (tid / WW) * WW;
    int h = h0 + row;
    int vf = (h == 0) ? 1 : ((h == HH - 1) ? 2 : 0);
    int hf = (col == 0) ? 1 : ((col == WW - 1) ? 2 : 0);
    int type = vf * 3 + hf;
    size_t gp0 = (size_t)n0 * PP + (size_t)h * WW + col;
    float kv0 = FIRST ? 0.f : kmap[gp0];
    float kv1 = FIRST ? 0.f : kmap[gp0 + PP];
    size_t obase0 = (size_t)n0 * CC * PP + (size_t)h * WW + col;

    int P[TO], Q[TO];
#pragma unroll
    for (int o = 0; o < TO; ++o) { P[o] = 0; Q[o] = 0; }

    // tap loop kept rolled (9 iters): I-cache friendly, bounded SGPR pressure
#pragma unroll 1
    for (int dr = 0; dr < 3; ++dr) {
#pragma unroll 1
        for (int dc = 0; dc < 3; ++dc) {
            int base = ((row + dr) * LW + (col + dc)) * W32;
            uint4 xa0 = *(const uint4*)&lds_x[base];
            uint4 xb0 = *(const uint4*)&lds_x[base + 4];
            uint4 xa1 = *(const uint4*)&lds_x[base + IMG];
            uint4 xb1 = *(const uint4*)&lds_x[base + IMG + 4];
            int t = dr * 3 + dc;
            const uint4* __restrict__ wq = (const uint4*)wbits + ((size_t)t * CC + o0) * 2;
#pragma unroll
            for (int o = 0; o < TO; ++o) {
                uint4 wa = wq[o * 2], wb2 = wq[o * 2 + 1];
                int s0 = P[o], s1 = Q[o];
                s0 += __popc(xa0.x ^ wa.x);
                s0 += __popc(xa0.y ^ wa.y);
                s0 += __popc(xa0.z ^ wa.z);
                s0 += __popc(xa0.w ^ wa.w);
                s0 += __popc(xb0.x ^ wb2.x);
                s0 += __popc(xb0.y ^ wb2.y);
                s0 += __popc(xb0.z ^ wb2.z);
                s0 += __popc(xb0.w ^ wb2.w);
                s1 += __popc(xa1.x ^ wa.x);
                s1 += __popc(xa1.y ^ wa.y);
                s1 += __popc(xa1.z ^ wa.z);
                s1 += __popc(xa1.w ^ wa.w);
                s1 += __popc(xb1.x ^ wb2.x);
                s1 += __popc(xb1.y ^ wb2.y);
                s1 += __popc(xb1.z ^ wb2.z);
                s1 += __popc(xb1.w ^ wb2.w);
                P[o] = s0; Q[o] = s1;
            }
        }
    }

#pragma unroll
    for (int o = 0; o < TO; ++o) {
        int oo = o0 + o;
        int adjv = adj[oo * 16 + type];
        int acc0 = adjv - 2 * P[o];
        int acc1 = adjv - 2 * Q[o];
        size_t oidx0 = obase0 + (size_t)oo * PP;
        size_t oidx1 = oidx0 + (size_t)CC * PP;
        if (FIRST) {
            out_i16[oidx0] = (short)acc0;
            out_i16[oidx1] = (short)acc1;
        } else {
            float al = alpha[oo];
            float r0 = al * kv0 * (float)acc0;
            float r1 = al * kv1 * (float)acc1;
            outf[oidx0] = fmaxf(r0 + ident[oidx0], 0.f);
            outf[oidx1] = fmaxf(r1 + ident[oidx1], 0.f);
        }
    }
}

extern "C" void kernel_launch(void* const* d_in, const int* in_sizes, int n_in,
                              void* d_out, int out_size, void* d_ws, size_t ws_size,
                              hipStream_t stream)
{
    const float* x  = (const float*)d_in[0];
    const float* g1 = (const float*)d_in[1];
    const float* b1 = (const float*)d_in[2];
    const float* w1 = (const float*)d_in[3];
    const float* g2 = (const float*)d_in[4];
    const float* b2 = (const float*)d_in[5];
    const float* w2 = (const float*)d_in[6];
    float* out = (float*)d_out;

    char* ws = (char*)d_ws;
    float* s1sum  = (float*)(ws + 0);
    float* s1sq   = (float*)(ws + 1024);
    float* s2sum  = (float*)(ws + 2048);
    float* s2sq   = (float*)(ws + 3072);
    float* scale1 = (float*)(ws + 4096);
    float* bias1  = (float*)(ws + 5120);
    float* scale2 = (float*)(ws + 6144);
    float* bias2  = (float*)(ws + 7168);
    float* alpha1 = (float*)(ws + 8192);
    float* alpha2 = (float*)(ws + 9216);
    int*   adj1   = (int*)(ws + 10240);                   // 16384 B
    int*   adj2   = (int*)(ws + 26624);                   // 16384 B
    uint32_t* wbits1 = (uint32_t*)(ws + 43008);           // 73728 B
    uint32_t* wbits2 = (uint32_t*)(ws + 116736);          // 73728 B
    float* a1 = (float*)(ws + 190464);                    // 401408 B
    float* k1 = (float*)(ws + 591872);
    float* a2 = (float*)(ws + 993280);
    float* k2 = (float*)(ws + 1394688);
    uint32_t* xbits1 = (uint32_t*)(ws + 1796096);         // 3211264 B
    uint32_t* xbits2 = (uint32_t*)(ws + 5007360);         // 3211264 B
    short* ci = (short*)(ws + 8218624);                   // 51380224 B

    hipMemsetAsync(ws, 0, 4096, stream);                  // zero stat accumulators
    k_wprep<<<2 * CC, 64, 0, stream>>>(w1, w2, wbits1, wbits2, alpha1, alpha2, adj1, adj2);
    k_stats<<<NB * CC, 256, 0, stream>>>(x, s1sum, s1sq);
    k_fin<<<1, 256, 0, stream>>>(s1sum, s1sq, g1, b1, scale1, bias1);
    k_bn1pack<<<NPIX / 64, 256, 0, stream>>>(x, scale1, bias1, xbits1, a1);
    k_box<<<NPIX / 256, 256, 0, stream>>>(a1, k1);
    k_conv<true><<<(NB / 2) * 7 * 16, 448, 0, stream>>>(xbits1, wbits1, adj1, nullptr, nullptr, ci, nullptr, nullptr);
    k_stats2<<<NB * CC, 256, 0, stream>>>(ci, alpha1, k1, s2sum, s2sq);
    k_fin<<<1, 256, 0, stream>>>(s2sum, s2sq, g2, b2, scale2, bias2);
    k_bn2pack<<<NPIX / 64, 256, 0, stream>>>(ci, alpha1, k1, scale2, bias2, xbits2, a2);
    k_box<<<NPIX / 256, 256, 0, stream>>>(a2, k2);
    k_conv<false><<<(NB / 2) * 7 * 16, 448, 0, stream>>>(xbits2, wbits2, adj2, alpha2, k2, nullptr, x, out);
}

// Round 5
// 538.304 us; speedup vs baseline: 1.5313x; 1.0592x over previous
//
#include <hip/hip_runtime.h>
#include <stdint.h>

#define NB 32
#define CC 256
#define HH 56
#define WW 56
#define PP (HH*WW)          // 3136
#define NPIX (NB*PP)        // 100352
#define W32 8               // 256 channels / 32 bits
#define KEPS 1e-5f

// ---------------- BN stats: per-(n,c) plane partial sums -> atomics ----------------
// float4-vectorized: 784 float4 per plane (16B/lane loads, G13)
__global__ void k_stats(const float* __restrict__ x, float* __restrict__ ssum, float* __restrict__ ssq) {
    int plane = blockIdx.x;               // n*CC + c
    int c = plane & (CC - 1);
    const float4* xp = (const float4*)(x + (size_t)plane * PP);
    float s = 0.f, q = 0.f;
    for (int i = threadIdx.x; i < PP / 4; i += blockDim.x) {
        float4 v = xp[i];
        s += v.x + v.y + v.z + v.w;
        q = fmaf(v.x, v.x, q); q = fmaf(v.y, v.y, q);
        q = fmaf(v.z, v.z, q); q = fmaf(v.w, v.w, q);
    }
#pragma unroll
    for (int off = 32; off; off >>= 1) { s += __shfl_down(s, off); q += __shfl_down(q, off); }
    __shared__ float ls[4], lq[4];
    int wv = threadIdx.x >> 6, ln = threadIdx.x & 63;
    if (ln == 0) { ls[wv] = s; lq[wv] = q; }
    __syncthreads();
    if (threadIdx.x == 0) {
        float S = 0.f, Q = 0.f;
        for (int w = 0; w < 4; ++w) { S += ls[w]; Q += lq[w]; }
        atomicAdd(&ssum[c], S); atomicAdd(&ssq[c], Q);
    }
}

// ---- BN2 stats from int16 conv sums: val = relu(alpha1[o]*k1[pix]*acc) ------------
// short4/float4-vectorized
__global__ void k_stats2(const short* __restrict__ ci, const float* __restrict__ alpha1,
                         const float* __restrict__ k1, float* __restrict__ ssum, float* __restrict__ ssq) {
    int plane = blockIdx.x;               // n*CC + o
    int o = plane & (CC - 1);
    int n = plane >> 8;
    const short4* cp = (const short4*)(ci + (size_t)plane * PP);
    const float4* kp = (const float4*)(k1 + (size_t)n * PP);
    float al = alpha1[o];
    float s = 0.f, q = 0.f;
    for (int i = threadIdx.x; i < PP / 4; i += blockDim.x) {
        short4 c4 = cp[i];
        float4 kf = kp[i];
        float v0 = fmaxf(al * kf.x * (float)c4.x, 0.f);
        float v1 = fmaxf(al * kf.y * (float)c4.y, 0.f);
        float v2 = fmaxf(al * kf.z * (float)c4.z, 0.f);
        float v3 = fmaxf(al * kf.w * (float)c4.w, 0.f);
        s += v0 + v1 + v2 + v3;
        q = fmaf(v0, v0, q); q = fmaf(v1, v1, q);
        q = fmaf(v2, v2, q); q = fmaf(v3, v3, q);
    }
#pragma unroll
    for (int off = 32; off; off >>= 1) { s += __shfl_down(s, off); q += __shfl_down(q, off); }
    __shared__ float ls[4], lq[4];
    int wv = threadIdx.x >> 6, ln = threadIdx.x & 63;
    if (ln == 0) { ls[wv] = s; lq[wv] = q; }
    __syncthreads();
    if (threadIdx.x == 0) {
        float S = 0.f, Q = 0.f;
        for (int w = 0; w < 4; ++w) { S += ls[w]; Q += lq[w]; }
        atomicAdd(&ssum[o], S); atomicAdd(&ssq[o], Q);
    }
}

// ---------------- weight prep: sign-pack + alpha + border-adjust table -------------
// Also zeroes the 4KB stats-accumulator region (blocks 0..15) so no memset
// dispatch is needed; stream order guarantees completion before k_stats.
// Layout: wb[(t*CC + o)*W32 + wd]  (tap-major).
// adj[o][type] = 256*nvalid(type) + 2 * sum_{t in invalid(type)} popc(wbits[o][t])
__global__ void k_wprep(const float* __restrict__ w1, const float* __restrict__ w2,
                        uint32_t* __restrict__ wb1, uint32_t* __restrict__ wb2,
                        float* __restrict__ al1, float* __restrict__ al2,
                        int* __restrict__ adj1, int* __restrict__ adj2,
                        float* __restrict__ zstats) {
    int o2 = blockIdx.x;                  // 0..511
    int lane = threadIdx.x;               // 64
    if (o2 < 16) zstats[o2 * 64 + lane] = 0.f;    // 1024 floats = s1sum..s2sq
    const float* w = (o2 < CC) ? w1 : w2;
    uint32_t* wb   = (o2 < CC) ? wb1 : wb2;
    float* al      = (o2 < CC) ? al1 : al2;
    int* adj       = (o2 < CC) ? adj1 : adj2;
    int o = o2 & (CC - 1);
    float asum = 0.f;
    int pt[9] = {0,0,0,0,0,0,0,0,0};      // popcount of sign bits per tap (all lanes)
    for (int cg = 0; cg < 4; ++cg) {
        int c = cg * 64 + lane;
        const float* wp = w + ((size_t)o * CC + c) * 9;
        for (int t = 0; t < 9; ++t) {
            float wv = wp[t];
            asum += fabsf(wv);
            unsigned long long m = __ballot(wv >= 0.0f);
            pt[t] += __popcll(m);
            if (lane == 0) {
                wb[(t * CC + o) * W32 + cg * 2]     = (uint32_t)m;
                wb[(t * CC + o) * W32 + cg * 2 + 1] = (uint32_t)(m >> 32);
            }
        }
    }
#pragma unroll
    for (int off = 32; off; off >>= 1) asum += __shfl_down(asum, off);
    if (lane == 0) al[o] = asum * (1.0f / 2304.0f);
    if (lane < 9) {
        const unsigned vm[3] = {0u, 0x007u, 0x1C0u};   // top rows / bottom rows
        const unsigned hm[3] = {0u, 0x049u, 0x124u};   // left cols / right cols
        unsigned mask = vm[lane / 3] | hm[lane % 3];
        int nv = 9 - __popc(mask);
        int wsum = 0;
#pragma unroll
        for (int t = 0; t < 9; ++t) if ((mask >> t) & 1) wsum += pt[t];
        adj[o * 16 + lane] = 256 * nv + 2 * wsum;
    }
}

// ------ BN1 finalize (inline) + apply + sign pack + channel-mean a1 ----------------
// 256-thread block: thread t computes scale/bias for channel t into LDS (redundant
// per block, deterministic, ~free) -> k_fin dispatch eliminated.
__global__ void k_bn1pack(const float* __restrict__ x,
                          const float* __restrict__ ssum, const float* __restrict__ ssq,
                          const float* __restrict__ gamma, const float* __restrict__ beta,
                          uint32_t* __restrict__ xbits, float* __restrict__ a) {
    __shared__ float sscale[CC], sbias[CC];
    {
        int t = threadIdx.x;
        float m   = ssum[t] * (1.0f / NPIX);
        float var = fmaf(-m, m, ssq[t] * (1.0f / NPIX));
        float sc  = gamma[t] / sqrtf(var + KEPS);
        sscale[t] = sc;
        sbias[t]  = fmaf(-m, sc, beta[t]);
    }
    __syncthreads();
    int lane = threadIdx.x & 63, wv = threadIdx.x >> 6;
    int n = blockIdx.x / 49;                        // 3136 = 49*64 pixels per image
    int pix = blockIdx.x * 64 + lane;
    int p = pix - n * PP;
    const float* xp = x + (size_t)n * CC * PP + p;
    uint32_t b0 = 0, b1 = 0;
    float asum = 0.f;
#pragma unroll
    for (int i = 0; i < 64; ++i) {
        int c = (wv << 6) + i;
        float v = xp[(size_t)c * PP];
        float bnv = fmaf(v, sscale[c], sbias[c]);
        asum += bnv;
        uint32_t bit = (bnv >= 0.0f) ? 1u : 0u;
        if (i < 32) b0 |= bit << i; else b1 |= bit << (i - 32);
    }
    ((uint2*)xbits)[(size_t)pix * 4 + wv] = make_uint2(b0, b1);
    __shared__ float lsum[4][64];
    lsum[wv][lane] = asum;
    __syncthreads();
    if (wv == 0)
        a[pix] = (lsum[0][lane] + lsum[1][lane] + lsum[2][lane] + lsum[3][lane]) * (1.0f / CC);
}

// ------ BN2 finalize (inline) + apply (recompute from int16 conv) + pack + a2 ------
__global__ void k_bn2pack(const short* __restrict__ ci, const float* __restrict__ alpha1,
                          const float* __restrict__ k1,
                          const float* __restrict__ ssum, const float* __restrict__ ssq,
                          const float* __restrict__ gamma, const float* __restrict__ beta,
                          uint32_t* __restrict__ xbits, float* __restrict__ a) {
    __shared__ float sscale[CC], sbias[CC];
    {
        int t = threadIdx.x;
        float m   = ssum[t] * (1.0f / NPIX);
        float var = fmaf(-m, m, ssq[t] * (1.0f / NPIX));
        float sc  = gamma[t] / sqrtf(var + KEPS);
        sscale[t] = sc;
        sbias[t]  = fmaf(-m, sc, beta[t]);
    }
    __syncthreads();
    int lane = threadIdx.x & 63, wv = threadIdx.x >> 6;
    int n = blockIdx.x / 49;
    int pix = blockIdx.x * 64 + lane;
    int p = pix - n * PP;
    const short* cp = ci + (size_t)n * CC * PP + p;
    float kv = k1[pix];
    uint32_t b0 = 0, b1 = 0;
    float asum = 0.f;
#pragma unroll
    for (int i = 0; i < 64; ++i) {
        int o = (wv << 6) + i;
        float val = fmaxf(alpha1[o] * kv * (float)cp[(size_t)o * PP], 0.f);
        float bnv = fmaf(val, sscale[o], sbias[o]);
        asum += bnv;
        uint32_t bit = (bnv >= 0.0f) ? 1u : 0u;
        if (i < 32) b0 |= bit << i; else b1 |= bit << (i - 32);
    }
    ((uint2*)xbits)[(size_t)pix * 4 + wv] = make_uint2(b0, b1);
    __shared__ float lsum[4][64];
    lsum[wv][lane] = asum;
    __syncthreads();
    if (wv == 0)
        a[pix] = (lsum[0][lane] + lsum[1][lane] + lsum[2][lane] + lsum[3][lane]) * (1.0f / CC);
}

// ---------------- 3x3 box filter (zero padded, /9) — only for k1 now ---------------
__global__ void k_box(const float* __restrict__ a, float* __restrict__ k) {
    int gid = blockIdx.x * 256 + threadIdx.x;    // NPIX
    int n = gid / PP;
    int p = gid - n * PP;
    int h = p / WW, w = p - (p / WW) * WW;
    const float* ap = a + (size_t)n * PP;
    float s = 0.f;
    for (int dr = -1; dr <= 1; ++dr) {
        int hh = h + dr;
        if (hh < 0 || hh >= HH) continue;
        for (int dc = -1; dc <= 1; ++dc) {
            int ww2 = w + dc;
            if (ww2 < 0 || ww2 >= WW) continue;
            s += ap[hh * WW + ww2];
        }
    }
    k[gid] = s * (1.0f / 9.0f);
}

// ---------------- binary conv core: tap-major, TO=16 (R2-proven structure) ---------
// block: 448 threads = 8 rows x 56 cols of pixels, fixed n, TO=16 output channels.
// For !FIRST, the K2 box filter is computed inline from the a-map (9 bounds-checked
// L2-hot loads per thread, once, outside the o/tap loops) -> k_box(k2) eliminated.
template<bool FIRST>
__global__ __launch_bounds__(448, 8) void k_conv(
    const uint32_t* __restrict__ xbits, const uint32_t* __restrict__ wbits,
    const int* __restrict__ adj, const float* __restrict__ alpha,
    const float* __restrict__ amap, short* __restrict__ out_i16,
    const float* __restrict__ ident, float* __restrict__ outf)
{
    constexpr int TH = 8, TO = 16;
    constexpr int LW = 58;                            // 56 + 2 col halo
    __shared__ uint32_t lds_x[(TH + 2) * LW * W32];   // 10*58*8*4 = 18560 B

    int b = blockIdx.x;
    int ob = b & 15, hb = (b >> 4) % 7, n = b / 112;
    int h0 = hb * TH, o0 = ob * TO;
    int tid = threadIdx.x;

    // stage rows h0-1..h0+TH, cols -1..56; zero outside image
    for (int i = tid; i < (TH + 2) * LW * 2; i += 448) {   // uint4 units, 116/row
        int r = i / (LW * 2), j = i - r * (LW * 2);
        int c = j >> 1, half = j & 1;
        int gr = h0 - 1 + r, gc = c - 1;
        uint4 v = make_uint4(0u, 0u, 0u, 0u);
        if (gr >= 0 && gr < HH && gc >= 0 && gc < WW)
            v = ((const uint4*)(xbits + ((size_t)n * PP + (size_t)gr * WW + gc) * W32))[half];
        ((uint4*)lds_x)[i] = v;
    }
    __syncthreads();

    int row = tid / WW, col = tid - (tid / WW) * WW;
    int h = h0 + row;
    int vf = (h == 0) ? 1 : ((h == HH - 1) ? 2 : 0);
    int hf = (col == 0) ? 1 : ((col == WW - 1) ? 2 : 0);
    int type = vf * 3 + hf;

    // inline 3x3 box of the channel-mean map (K2) for the epilogue
    float kv = 0.f;
    if (!FIRST) {
        const float* ap = amap + (size_t)n * PP;
        float s = 0.f;
        for (int dr = -1; dr <= 1; ++dr) {
            int hh = h + dr;
            if (hh < 0 || hh >= HH) continue;
            for (int dc2 = -1; dc2 <= 1; ++dc2) {
                int wc = col + dc2;
                if (wc < 0 || wc >= WW) continue;
                s += ap[hh * WW + wc];
            }
        }
        kv = s * (1.0f / 9.0f);
    }
    size_t obase = (size_t)n * CC * PP + (size_t)h * WW + col;

    int P[TO];
#pragma unroll
    for (int o = 0; o < TO; ++o) P[o] = 0;

    // tap loop kept rolled (9 iters): I-cache friendly, bounded SGPR pressure
#pragma unroll 1
    for (int dr = 0; dr < 3; ++dr) {
#pragma unroll 1
        for (int dc = 0; dc < 3; ++dc) {
            int base = ((row + dr) * LW + (col + dc)) * W32;
            uint4 xa = *(const uint4*)&lds_x[base];
            uint4 xb = *(const uint4*)&lds_x[base + 4];
            int t = dr * 3 + dc;
            const uint4* __restrict__ wq = (const uint4*)wbits + ((size_t)t * CC + o0) * 2;
#pragma unroll
            for (int o = 0; o < TO; ++o) {
                uint4 wa = wq[o * 2], wb2 = wq[o * 2 + 1];
                int P0 = P[o];
                P0 += __popc(xa.x ^ wa.x);
                P0 += __popc(xa.y ^ wa.y);
                P0 += __popc(xa.z ^ wa.z);
                P0 += __popc(xa.w ^ wa.w);
                P0 += __popc(xb.x ^ wb2.x);
                P0 += __popc(xb.y ^ wb2.y);
                P0 += __popc(xb.z ^ wb2.z);
                P0 += __popc(xb.w ^ wb2.w);
                P[o] = P0;
            }
        }
    }

#pragma unroll
    for (int o = 0; o < TO; ++o) {
        int oo = o0 + o;
        int acc = adj[oo * 16 + type] - 2 * P[o];
        size_t oidx = obase + (size_t)oo * PP;
        if (FIRST) {
            out_i16[oidx] = (short)acc;
        } else {
            float res = alpha[oo] * kv * (float)acc;
            outf[oidx] = fmaxf(res + ident[oidx], 0.f);
        }
    }
}

extern "C" void kernel_launch(void* const* d_in, const int* in_sizes, int n_in,
                              void* d_out, int out_size, void* d_ws, size_t ws_size,
                              hipStream_t stream)
{
    const float* x  = (const float*)d_in[0];
    const float* g1 = (const float*)d_in[1];
    const float* b1 = (const float*)d_in[2];
    const float* w1 = (const float*)d_in[3];
    const float* g2 = (const float*)d_in[4];
    const float* b2 = (const float*)d_in[5];
    const float* w2 = (const float*)d_in[6];
    float* out = (float*)d_out;

    char* ws = (char*)d_ws;
    float* s1sum  = (float*)(ws + 0);
    float* s1sq   = (float*)(ws + 1024);
    float* s2sum  = (float*)(ws + 2048);
    float* s2sq   = (float*)(ws + 3072);
    float* alpha1 = (float*)(ws + 8192);
    float* alpha2 = (float*)(ws + 9216);
    int*   adj1   = (int*)(ws + 10240);                   // 16384 B
    int*   adj2   = (int*)(ws + 26624);                   // 16384 B
    uint32_t* wbits1 = (uint32_t*)(ws + 43008);           // 73728 B
    uint32_t* wbits2 = (uint32_t*)(ws + 116736);          // 73728 B
    float* a1 = (float*)(ws + 190464);                    // 401408 B
    float* k1 = (float*)(ws + 591872);
    float* a2 = (float*)(ws + 993280);
    uint32_t* xbits1 = (uint32_t*)(ws + 1796096);         // 3211264 B
    uint32_t* xbits2 = (uint32_t*)(ws + 5007360);         // 3211264 B
    short* ci = (short*)(ws + 8218624);                   // 51380224 B

    // 8 dispatches (was 13): memset folded into wprep; fin x2 folded into packs;
    // box(k2) folded into conv<false>.
    k_wprep<<<2 * CC, 64, 0, stream>>>(w1, w2, wbits1, wbits2, alpha1, alpha2, adj1, adj2, s1sum);
    k_stats<<<NB * CC, 256, 0, stream>>>(x, s1sum, s1sq);
    k_bn1pack<<<NPIX / 64, 256, 0, stream>>>(x, s1sum, s1sq, g1, b1, xbits1, a1);
    k_box<<<NPIX / 256, 256, 0, stream>>>(a1, k1);
    k_conv<true><<<NB * 7 * 16, 448, 0, stream>>>(xbits1, wbits1, adj1, nullptr, nullptr, ci, nullptr, nullptr);
    k_stats2<<<NB * CC, 256, 0, stream>>>(ci, alpha1, k1, s2sum, s2sq);
    k_bn2pack<<<NPIX / 64, 256, 0, stream>>>(ci, alpha1, k1, s2sum, s2sq, g2, b2, xbits2, a2);
    k_conv<false><<<NB * 7 * 16, 448, 0, stream>>>(xbits2, wbits2, adj2, alpha2, a2, nullptr, x, out);
}

// Round 6
// 490.499 us; speedup vs baseline: 1.6805x; 1.0975x over previous
//
#include <hip/hip_runtime.h>
#include <stdint.h>

#define NB 32
#define CC 256
#define HH 56
#define WW 56
#define PP (HH*WW)          // 3136
#define NPIX (NB*PP)        // 100352
#define W32 8               // 256 channels / 32 bits (popcount fallback path)
#define KEPS 1e-5f

typedef __attribute__((ext_vector_type(4)))  int i32x4;
typedef __attribute__((ext_vector_type(16))) int i32x16;

// =========================== shared kernels (both paths) ===========================

// BN stats: per-(n,c) plane partial sums -> atomics. float4-vectorized.
__global__ void k_stats(const float* __restrict__ x, float* __restrict__ ssum, float* __restrict__ ssq) {
    int plane = blockIdx.x;               // n*CC + c
    int c = plane & (CC - 1);
    const float4* xp = (const float4*)(x + (size_t)plane * PP);
    float s = 0.f, q = 0.f;
    for (int i = threadIdx.x; i < PP / 4; i += blockDim.x) {
        float4 v = xp[i];
        s += v.x + v.y + v.z + v.w;
        q = fmaf(v.x, v.x, q); q = fmaf(v.y, v.y, q);
        q = fmaf(v.z, v.z, q); q = fmaf(v.w, v.w, q);
    }
#pragma unroll
    for (int off = 32; off; off >>= 1) { s += __shfl_down(s, off); q += __shfl_down(q, off); }
    __shared__ float ls[4], lq[4];
    int wv = threadIdx.x >> 6, ln = threadIdx.x & 63;
    if (ln == 0) { ls[wv] = s; lq[wv] = q; }
    __syncthreads();
    if (threadIdx.x == 0) {
        float S = 0.f, Q = 0.f;
        for (int w = 0; w < 4; ++w) { S += ls[w]; Q += lq[w]; }
        atomicAdd(&ssum[c], S); atomicAdd(&ssq[c], Q);
    }
}

// BN2 stats from int16 conv sums: val = relu(alpha1[o]*k1[pix]*acc). short4/float4.
__global__ void k_stats2(const short* __restrict__ ci, const float* __restrict__ alpha1,
                         const float* __restrict__ k1, float* __restrict__ ssum, float* __restrict__ ssq) {
    int plane = blockIdx.x;               // n*CC + o
    int o = plane & (CC - 1);
    int n = plane >> 8;
    const short4* cp = (const short4*)(ci + (size_t)plane * PP);
    const float4* kp = (const float4*)(k1 + (size_t)n * PP);
    float al = alpha1[o];
    float s = 0.f, q = 0.f;
    for (int i = threadIdx.x; i < PP / 4; i += blockDim.x) {
        short4 c4 = cp[i];
        float4 kf = kp[i];
        float v0 = fmaxf(al * kf.x * (float)c4.x, 0.f);
        float v1 = fmaxf(al * kf.y * (float)c4.y, 0.f);
        float v2 = fmaxf(al * kf.z * (float)c4.z, 0.f);
        float v3 = fmaxf(al * kf.w * (float)c4.w, 0.f);
        s += v0 + v1 + v2 + v3;
        q = fmaf(v0, v0, q); q = fmaf(v1, v1, q);
        q = fmaf(v2, v2, q); q = fmaf(v3, v3, q);
    }
#pragma unroll
    for (int off = 32; off; off >>= 1) { s += __shfl_down(s, off); q += __shfl_down(q, off); }
    __shared__ float ls[4], lq[4];
    int wv = threadIdx.x >> 6, ln = threadIdx.x & 63;
    if (ln == 0) { ls[wv] = s; lq[wv] = q; }
    __syncthreads();
    if (threadIdx.x == 0) {
        float S = 0.f, Q = 0.f;
        for (int w = 0; w < 4; ++w) { S += ls[w]; Q += lq[w]; }
        atomicAdd(&ssum[o], S); atomicAdd(&ssq[o], Q);
    }
}

// 3x3 box filter (zero padded, /9)
__global__ void k_box(const float* __restrict__ a, float* __restrict__ k) {
    int gid = blockIdx.x * 256 + threadIdx.x;    // NPIX
    int n = gid / PP;
    int p = gid - n * PP;
    int h = p / WW, w = p - (p / WW) * WW;
    const float* ap = a + (size_t)n * PP;
    float s = 0.f;
    for (int dr = -1; dr <= 1; ++dr) {
        int hh = h + dr;
        if (hh < 0 || hh >= HH) continue;
        for (int dc = -1; dc <= 1; ++dc) {
            int ww2 = w + dc;
            if (ww2 < 0 || ww2 >= WW) continue;
            s += ap[hh * WW + ww2];
        }
    }
    k[gid] = s * (1.0f / 9.0f);
}

// ================================ MFMA path ========================================
// Weight prep: sign as i8 in exact B-fragment order wpack[t][k32][oc][kh][16B],
// where channel ch = k32*32 + kh*16 + j.  Also alpha and the stats-zeroing.
__global__ void k_wprepM(const float* __restrict__ w1, const float* __restrict__ w2,
                         uint8_t* __restrict__ wp1, uint8_t* __restrict__ wp2,
                         float* __restrict__ al1, float* __restrict__ al2,
                         float* __restrict__ zstats) {
    int o2 = blockIdx.x;                  // 0..511
    int lane = threadIdx.x;               // 64
    if (o2 < 16) zstats[o2 * 64 + lane] = 0.f;    // 4KB stats region
    const float* w = (o2 < CC) ? w1 : w2;
    uint8_t* wp    = (o2 < CC) ? wp1 : wp2;
    float* al      = (o2 < CC) ? al1 : al2;
    int o = o2 & (CC - 1);
    float asum = 0.f;
    for (int cg = 0; cg < 4; ++cg) {
        int c = cg * 64 + lane;
        const float* wpt = w + ((size_t)o * CC + c) * 9;
        int c32 = c >> 5;                 // k32 index of this channel
        int rem = c & 31;                 // kh*16 + j
        for (int t = 0; t < 9; ++t) {
            float wv = wpt[t];
            asum += fabsf(wv);
            int kg = t * 8 + c32;
            wp[((size_t)kg * CC + o) * 32 + rem] = (wv >= 0.0f) ? (uint8_t)1 : (uint8_t)0xFF;
        }
    }
#pragma unroll
    for (int off = 32; off; off >>= 1) asum += __shfl_down(asum, off);
    if (lane == 0) al[o] = asum * (1.0f / 2304.0f);
}

// BN1 finalize + apply + i8 binarize (+1/-1) into [pixel][channel] layout + mean a1.
// LDS transpose: compute channel-major, write out pixel-major coalesced.
__global__ void k_bn1packM(const float* __restrict__ x,
                           const float* __restrict__ ssum, const float* __restrict__ ssq,
                           const float* __restrict__ gamma, const float* __restrict__ beta,
                           uint8_t* __restrict__ xi8, float* __restrict__ a) {
    __shared__ float sscale[CC], sbias[CC];
    __shared__ uint32_t ldsT[64][68];     // 64 px x 64 dwords (+4 dw pad vs bank conflicts)
    __shared__ float lsum[4][64];
    int t = threadIdx.x;
    {
        float m   = ssum[t] * (1.0f / NPIX);
        float var = fmaf(-m, m, ssq[t] * (1.0f / NPIX));
        float sc  = gamma[t] / sqrtf(var + KEPS);
        sscale[t] = sc;
        sbias[t]  = fmaf(-m, sc, beta[t]);
    }
    __syncthreads();
    int lane = t & 63, wv = t >> 6;
    int n = blockIdx.x / 49;              // 49 blocks * 64 px = 3136 px per image
    int pix = blockIdx.x * 64 + lane;
    int p = pix - n * PP;
    const float* xp = x + (size_t)n * CC * PP + p;
    float asum = 0.f;
    for (int i4 = 0; i4 < 16; ++i4) {
        uint32_t pk = 0;
#pragma unroll
        for (int u = 0; u < 4; ++u) {
            int c = (wv << 6) + i4 * 4 + u;
            float v = xp[(size_t)c * PP];
            float bnv = fmaf(v, sscale[c], sbias[c]);
            asum += bnv;
            uint32_t byte = (bnv >= 0.0f) ? 0x01u : 0xFFu;
            pk |= byte << (8 * u);
        }
        ldsT[lane][(wv << 4) + i4] = pk;
    }
    lsum[wv][lane] = asum;
    __syncthreads();
    if (wv == 0)
        a[pix] = (lsum[0][lane] + lsum[1][lane] + lsum[2][lane] + lsum[3][lane]) * (1.0f / CC);
    // write out 64 px * 256 B, coalesced
    size_t gbase = (size_t)blockIdx.x * 64 * CC;
    for (int it = 0; it < 4; ++it) {
        int idx4 = it * 256 + t;          // 0..1023 uint4 units
        int px = idx4 >> 4, j = idx4 & 15;
        uint4 v = *(uint4*)&ldsT[px][j * 4];
        *(uint4*)(xi8 + gbase + (size_t)px * CC + j * 16) = v;
    }
}

// BN2 finalize + apply (recompute val from int16 conv) + i8 binarize + mean a2.
__global__ void k_bn2packM(const short* __restrict__ ci, const float* __restrict__ alpha1,
                           const float* __restrict__ k1,
                           const float* __restrict__ ssum, const float* __restrict__ ssq,
                           const float* __restrict__ gamma, const float* __restrict__ beta,
                           uint8_t* __restrict__ xi8, float* __restrict__ a) {
    __shared__ float sscale[CC], sbias[CC], salpha[CC];
    __shared__ uint32_t ldsT[64][68];
    __shared__ float lsum[4][64];
    int t = threadIdx.x;
    {
        float m   = ssum[t] * (1.0f / NPIX);
        float var = fmaf(-m, m, ssq[t] * (1.0f / NPIX));
        float sc  = gamma[t] / sqrtf(var + KEPS);
        sscale[t] = sc;
        sbias[t]  = fmaf(-m, sc, beta[t]);
        salpha[t] = alpha1[t];
    }
    __syncthreads();
    int lane = t & 63, wv = t >> 6;
    int n = blockIdx.x / 49;
    int pix = blockIdx.x * 64 + lane;
    int p = pix - n * PP;
    const short* cp = ci + (size_t)n * CC * PP + p;
    float kv = k1[pix];
    float asum = 0.f;
    for (int i4 = 0; i4 < 16; ++i4) {
        uint32_t pk = 0;
#pragma unroll
        for (int u = 0; u < 4; ++u) {
            int c = (wv << 6) + i4 * 4 + u;
            float val = fmaxf(salpha[c] * kv * (float)cp[(size_t)c * PP], 0.f);
            float bnv = fmaf(val, sscale[c], sbias[c]);
            asum += bnv;
            uint32_t byte = (bnv >= 0.0f) ? 0x01u : 0xFFu;
            pk |= byte << (8 * u);
        }
        ldsT[lane][(wv << 4) + i4] = pk;
    }
    lsum[wv][lane] = asum;
    __syncthreads();
    if (wv == 0)
        a[pix] = (lsum[0][lane] + lsum[1][lane] + lsum[2][lane] + lsum[3][lane]) * (1.0f / CC);
    size_t gbase = (size_t)blockIdx.x * 64 * CC;
    for (int it = 0; it < 4; ++it) {
        int idx4 = it * 256 + t;
        int px = idx4 >> 4, j = idx4 & 15;
        uint4 v = *(uint4*)&ldsT[px][j * 4];
        *(uint4*)(xi8 + gbase + (size_t)px * CC + j * 16) = v;
    }
}

// MFMA binary conv: implicit GEMM, exact i8 ±1 inputs, i32 accumulate.
// Block: 448 thr = 7 waves; tile = 4 rows x 56 cols = 224 px (7 m-subtiles of 32);
// each block does one N-half (128 oc = 4 col-tiles of 32). K = 9 taps x 256 ch,
// staged from LDS halo tile (6x58 px, 64-ch chunks, 80 B/px pitch).
// Zero-padding = staged i8 zeros (no border adjust table needed).
template<bool FIRST>
__global__ __launch_bounds__(448, 4) void k_convM(
    const uint8_t* __restrict__ xi8, const uint8_t* __restrict__ wpack,
    const float* __restrict__ alpha, const float* __restrict__ kmap,
    short* __restrict__ out_i16, const float* __restrict__ ident,
    float* __restrict__ outf)
{
    constexpr int PITCH = 80;                       // 64 data + 16 pad bytes per px slot
    __shared__ uint8_t lds8[6 * 58 * PITCH];        // 27840 B

    int b = blockIdx.x;
    int nh = b & 1;
    int hb = (b >> 1) % 14;
    int n  = b / 28;
    int h0 = hb * 4;
    int tid = threadIdx.x;
    int wvi = tid >> 6, lane = tid & 63;
    int l31 = lane & 31, kh = lane >> 5;

    // lane's pixel within tile for A-fragment reads
    int pidx = wvi * 32 + l31;                      // 0..223
    int r_l = pidx / 56, c_l = pidx - (pidx / 56) * 56;

    i32x16 acc[4] = {};                             // 4 col-tiles of 32 oc

#pragma unroll 1
    for (int kb = 0; kb < 4; ++kb) {                // 64-channel chunks
        __syncthreads();
        // stage 6x58 pixel slots, 4 x uint4 each, channel chunk kb*64
        for (int i = tid; i < 6 * 58 * 4; i += 448) {
            int slot = i >> 2, j = i & 3;
            int r = slot / 58, c = slot - (slot / 58) * 58;
            int gr = h0 - 1 + r, gc = c - 1;
            uint4 v = make_uint4(0u, 0u, 0u, 0u);
            if (gr >= 0 && gr < HH && gc >= 0 && gc < WW)
                v = *(const uint4*)(xi8 + (size_t)(n * PP + gr * WW + gc) * CC + kb * 64 + j * 16);
            *(uint4*)(lds8 + slot * PITCH + j * 16) = v;
        }
        __syncthreads();
#pragma unroll 1
        for (int t = 0; t < 9; ++t) {
            int dr = t / 3, dc = t - (t / 3) * 3;
            int aoff = ((r_l + dr) * 58 + (c_l + dc)) * PITCH + kh * 16;
#pragma unroll
            for (int k32 = 0; k32 < 2; ++k32) {
                i32x4 af = *(const i32x4*)(lds8 + aoff + k32 * 32);
                int kg = t * 8 + kb * 2 + k32;
                const uint8_t* wp = wpack + ((size_t)kg * CC + nh * 128 + l31) * 32 + kh * 16;
#pragma unroll
                for (int ct = 0; ct < 4; ++ct) {
                    i32x4 bf = *(const i32x4*)(wp + ct * 32 * 32);
                    acc[ct] = __builtin_amdgcn_mfma_i32_32x32x32_i8(af, bf, acc[ct], 0, 0, 0);
                }
            }
        }
    }

    // epilogue: C/D layout col=lane&31(=oc), row=(reg&3)+8*(reg>>2)+4*kh (=pixel m)
    int pbase = h0 * WW + wvi * 32;
#pragma unroll
    for (int ct = 0; ct < 4; ++ct) {
        int oc = nh * 128 + ct * 32 + l31;
        size_t obase = ((size_t)n * CC + oc) * PP;
        float al = 0.f;
        if (!FIRST) al = alpha[oc];
#pragma unroll
        for (int rg = 0; rg < 16; ++rg) {
            int m = (rg & 3) + 8 * (rg >> 2) + 4 * kh;
            int p = pbase + m;
            int acv = acc[ct][rg];
            if (FIRST) {
                out_i16[obase + p] = (short)acv;
            } else {
                float kv = kmap[(size_t)n * PP + p];
                float r = al * kv * (float)acv;
                outf[obase + p] = fmaxf(r + ident[obase + p], 0.f);
            }
        }
    }
}

// ====================== popcount fallback path (R5, proven) ========================
__global__ void k_wprepP(const float* __restrict__ w1, const float* __restrict__ w2,
                         uint32_t* __restrict__ wb1, uint32_t* __restrict__ wb2,
                         float* __restrict__ al1, float* __restrict__ al2,
                         int* __restrict__ adj1, int* __restrict__ adj2,
                         float* __restrict__ zstats) {
    int o2 = blockIdx.x;
    int lane = threadIdx.x;
    if (o2 < 16) zstats[o2 * 64 + lane] = 0.f;
    const float* w = (o2 < CC) ? w1 : w2;
    uint32_t* wb   = (o2 < CC) ? wb1 : wb2;
    float* al      = (o2 < CC) ? al1 : al2;
    int* adj       = (o2 < CC) ? adj1 : adj2;
    int o = o2 & (CC - 1);
    float asum = 0.f;
    int pt[9] = {0,0,0,0,0,0,0,0,0};
    for (int cg = 0; cg < 4; ++cg) {
        int c = cg * 64 + lane;
        const float* wp = w + ((size_t)o * CC + c) * 9;
        for (int t = 0; t < 9; ++t) {
            float wv = wp[t];
            asum += fabsf(wv);
            unsigned long long m = __ballot(wv >= 0.0f);
            pt[t] += __popcll(m);
            if (lane == 0) {
                wb[(t * CC + o) * W32 + cg * 2]     = (uint32_t)m;
                wb[(t * CC + o) * W32 + cg * 2 + 1] = (uint32_t)(m >> 32);
            }
        }
    }
#pragma unroll
    for (int off = 32; off; off >>= 1) asum += __shfl_down(asum, off);
    if (lane == 0) al[o] = asum * (1.0f / 2304.0f);
    if (lane < 9) {
        const unsigned vm[3] = {0u, 0x007u, 0x1C0u};
        const unsigned hm[3] = {0u, 0x049u, 0x124u};
        unsigned mask = vm[lane / 3] | hm[lane % 3];
        int nv = 9 - __popc(mask);
        int wsum = 0;
#pragma unroll
        for (int t = 0; t < 9; ++t) if ((mask >> t) & 1) wsum += pt[t];
        adj[o * 16 + lane] = 256 * nv + 2 * wsum;
    }
}

__global__ void k_bn1packP(const float* __restrict__ x,
                           const float* __restrict__ ssum, const float* __restrict__ ssq,
                           const float* __restrict__ gamma, const float* __restrict__ beta,
                           uint32_t* __restrict__ xbits, float* __restrict__ a) {
    __shared__ float sscale[CC], sbias[CC];
    {
        int t = threadIdx.x;
        float m   = ssum[t] * (1.0f / NPIX);
        float var = fmaf(-m, m, ssq[t] * (1.0f / NPIX));
        float sc  = gamma[t] / sqrtf(var + KEPS);
        sscale[t] = sc;
        sbias[t]  = fmaf(-m, sc, beta[t]);
    }
    __syncthreads();
    int lane = threadIdx.x & 63, wv = threadIdx.x >> 6;
    int n = blockIdx.x / 49;
    int pix = blockIdx.x * 64 + lane;
    int p = pix - n * PP;
    const float* xp = x + (size_t)n * CC * PP + p;
    uint32_t b0 = 0, b1 = 0;
    float asum = 0.f;
#pragma unroll
    for (int i = 0; i < 64; ++i) {
        int c = (wv << 6) + i;
        float v = xp[(size_t)c * PP];
        float bnv = fmaf(v, sscale[c], sbias[c]);
        asum += bnv;
        uint32_t bit = (bnv >= 0.0f) ? 1u : 0u;
        if (i < 32) b0 |= bit << i; else b1 |= bit << (i - 32);
    }
    ((uint2*)xbits)[(size_t)pix * 4 + wv] = make_uint2(b0, b1);
    __shared__ float lsum[4][64];
    lsum[wv][lane] = asum;
    __syncthreads();
    if (wv == 0)
        a[pix] = (lsum[0][lane] + lsum[1][lane] + lsum[2][lane] + lsum[3][lane]) * (1.0f / CC);
}

__global__ void k_bn2packP(const short* __restrict__ ci, const float* __restrict__ alpha1,
                           const float* __restrict__ k1,
                           const float* __restrict__ ssum, const float* __restrict__ ssq,
                           const float* __restrict__ gamma, const float* __restrict__ beta,
                           uint32_t* __restrict__ xbits, float* __restrict__ a) {
    __shared__ float sscale[CC], sbias[CC];
    {
        int t = threadIdx.x;
        float m   = ssum[t] * (1.0f / NPIX);
        float var = fmaf(-m, m, ssq[t] * (1.0f / NPIX));
        float sc  = gamma[t] / sqrtf(var + KEPS);
        sscale[t] = sc;
        sbias[t]  = fmaf(-m, sc, beta[t]);
    }
    __syncthreads();
    int lane = threadIdx.x & 63, wv = threadIdx.x >> 6;
    int n = blockIdx.x / 49;
    int pix = blockIdx.x * 64 + lane;
    int p = pix - n * PP;
    const short* cp = ci + (size_t)n * CC * PP + p;
    float kv = k1[pix];
    uint32_t b0 = 0, b1 = 0;
    float asum = 0.f;
#pragma unroll
    for (int i = 0; i < 64; ++i) {
        int o = (wv << 6) + i;
        float val = fmaxf(alpha1[o] * kv * (float)cp[(size_t)o * PP], 0.f);
        float bnv = fmaf(val, sscale[o], sbias[o]);
        asum += bnv;
        uint32_t bit = (bnv >= 0.0f) ? 1u : 0u;
        if (i < 32) b0 |= bit << i; else b1 |= bit << (i - 32);
    }
    ((uint2*)xbits)[(size_t)pix * 4 + wv] = make_uint2(b0, b1);
    __shared__ float lsum[4][64];
    lsum[wv][lane] = asum;
    __syncthreads();
    if (wv == 0)
        a[pix] = (lsum[0][lane] + lsum[1][lane] + lsum[2][lane] + lsum[3][lane]) * (1.0f / CC);
}

template<bool FIRST>
__global__ __launch_bounds__(448, 8) void k_convP(
    const uint32_t* __restrict__ xbits, const uint32_t* __restrict__ wbits,
    const int* __restrict__ adj, const float* __restrict__ alpha,
    const float* __restrict__ amap, short* __restrict__ out_i16,
    const float* __restrict__ ident, float* __restrict__ outf)
{
    constexpr int TH = 8, TO = 16;
    constexpr int LW = 58;
    __shared__ uint32_t lds_x[(TH + 2) * LW * W32];

    int b = blockIdx.x;
    int ob = b & 15, hb = (b >> 4) % 7, n = b / 112;
    int h0 = hb * TH, o0 = ob * TO;
    int tid = threadIdx.x;

    for (int i = tid; i < (TH + 2) * LW * 2; i += 448) {
        int r = i / (LW * 2), j = i - r * (LW * 2);
        int c = j >> 1, half = j & 1;
        int gr = h0 - 1 + r, gc = c - 1;
        uint4 v = make_uint4(0u, 0u, 0u, 0u);
        if (gr >= 0 && gr < HH && gc >= 0 && gc < WW)
            v = ((const uint4*)(xbits + ((size_t)n * PP + (size_t)gr * WW + gc) * W32))[half];
        ((uint4*)lds_x)[i] = v;
    }
    __syncthreads();

    int row = tid / WW, col = tid - (tid / WW) * WW;
    int h = h0 + row;
    int vf = (h == 0) ? 1 : ((h == HH - 1) ? 2 : 0);
    int hf = (col == 0) ? 1 : ((col == WW - 1) ? 2 : 0);
    int type = vf * 3 + hf;

    float kv = 0.f;
    if (!FIRST) {
        const float* ap = amap + (size_t)n * PP;
        float s = 0.f;
        for (int dr = -1; dr <= 1; ++dr) {
            int hh = h + dr;
            if (hh < 0 || hh >= HH) continue;
            for (int dc2 = -1; dc2 <= 1; ++dc2) {
                int wc = col + dc2;
                if (wc < 0 || wc >= WW) continue;
                s += ap[hh * WW + wc];
            }
        }
        kv = s * (1.0f / 9.0f);
    }
    size_t obase = (size_t)n * CC * PP + (size_t)h * WW + col;

    int P[TO];
#pragma unroll
    for (int o = 0; o < TO; ++o) P[o] = 0;

#pragma unroll 1
    for (int dr = 0; dr < 3; ++dr) {
#pragma unroll 1
        for (int dc = 0; dc < 3; ++dc) {
            int base = ((row + dr) * LW + (col + dc)) * W32;
            uint4 xa = *(const uint4*)&lds_x[base];
            uint4 xb = *(const uint4*)&lds_x[base + 4];
            int t = dr * 3 + dc;
            const uint4* __restrict__ wq = (const uint4*)wbits + ((size_t)t * CC + o0) * 2;
#pragma unroll
            for (int o = 0; o < TO; ++o) {
                uint4 wa = wq[o * 2], wb2 = wq[o * 2 + 1];
                int P0 = P[o];
                P0 += __popc(xa.x ^ wa.x);
                P0 += __popc(xa.y ^ wa.y);
                P0 += __popc(xa.z ^ wa.z);
                P0 += __popc(xa.w ^ wa.w);
                P0 += __popc(xb.x ^ wb2.x);
                P0 += __popc(xb.y ^ wb2.y);
                P0 += __popc(xb.z ^ wb2.z);
                P0 += __popc(xb.w ^ wb2.w);
                P[o] = P0;
            }
        }
    }

#pragma unroll
    for (int o = 0; o < TO; ++o) {
        int oo = o0 + o;
        int acc = adj[oo * 16 + type] - 2 * P[o];
        size_t oidx = obase + (size_t)oo * PP;
        if (FIRST) {
            out_i16[oidx] = (short)acc;
        } else {
            float res = alpha[oo] * kv * (float)acc;
            outf[oidx] = fmaxf(res + ident[oidx], 0.f);
        }
    }
}

// ================================= launcher ========================================
extern "C" void kernel_launch(void* const* d_in, const int* in_sizes, int n_in,
                              void* d_out, int out_size, void* d_ws, size_t ws_size,
                              hipStream_t stream)
{
    const float* x  = (const float*)d_in[0];
    const float* g1 = (const float*)d_in[1];
    const float* b1 = (const float*)d_in[2];
    const float* w1 = (const float*)d_in[3];
    const float* g2 = (const float*)d_in[4];
    const float* b2 = (const float*)d_in[5];
    const float* w2 = (const float*)d_in[6];
    float* out = (float*)d_out;
    char* ws = (char*)d_ws;

    const size_t MFMA_NEED = 79872000;   // see layout below (~76.2 MB)

    if (ws_size >= MFMA_NEED) {
        // ---- MFMA path ----
        float* s1sum  = (float*)(ws + 0);
        float* s1sq   = (float*)(ws + 1024);
        float* s2sum  = (float*)(ws + 2048);
        float* s2sq   = (float*)(ws + 3072);
        float* alpha1 = (float*)(ws + 8192);
        float* alpha2 = (float*)(ws + 9216);
        uint8_t* wp1  = (uint8_t*)(ws + 16384);           // 589824 B
        uint8_t* wp2  = (uint8_t*)(ws + 606208);          // 589824 B
        float* a1     = (float*)(ws + 1196032);           // 401408 B
        float* k1     = (float*)(ws + 1597440);
        float* a2     = (float*)(ws + 1998848);
        float* k2     = (float*)(ws + 2400256);
        uint8_t* xi8  = (uint8_t*)(ws + 2801664);         // 25690112 B (reused both layers)
        short* ci     = (short*)(ws + 28491776);          // 51380224 B -> ends 79872000

        k_wprepM<<<2 * CC, 64, 0, stream>>>(w1, w2, wp1, wp2, alpha1, alpha2, s1sum);
        k_stats<<<NB * CC, 256, 0, stream>>>(x, s1sum, s1sq);
        k_bn1packM<<<NPIX / 64, 256, 0, stream>>>(x, s1sum, s1sq, g1, b1, xi8, a1);
        k_box<<<NPIX / 256, 256, 0, stream>>>(a1, k1);
        k_convM<true><<<NB * 14 * 2, 448, 0, stream>>>(xi8, wp1, nullptr, nullptr, ci, nullptr, nullptr);
        k_stats2<<<NB * CC, 256, 0, stream>>>(ci, alpha1, k1, s2sum, s2sq);
        k_bn2packM<<<NPIX / 64, 256, 0, stream>>>(ci, alpha1, k1, s2sum, s2sq, g2, b2, xi8, a2);
        k_box<<<NPIX / 256, 256, 0, stream>>>(a2, k2);
        k_convM<false><<<NB * 14 * 2, 448, 0, stream>>>(xi8, wp2, alpha2, k2, nullptr, x, out);
    } else {
        // ---- popcount fallback (R5 layout) ----
        float* s1sum  = (float*)(ws + 0);
        float* s1sq   = (float*)(ws + 1024);
        float* s2sum  = (float*)(ws + 2048);
        float* s2sq   = (float*)(ws + 3072);
        float* alpha1 = (float*)(ws + 8192);
        float* alpha2 = (float*)(ws + 9216);
        int*   adj1   = (int*)(ws + 10240);
        int*   adj2   = (int*)(ws + 26624);
        uint32_t* wbits1 = (uint32_t*)(ws + 43008);
        uint32_t* wbits2 = (uint32_t*)(ws + 116736);
        float* a1 = (float*)(ws + 190464);
        float* k1 = (float*)(ws + 591872);
        float* a2 = (float*)(ws + 993280);
        uint32_t* xbits1 = (uint32_t*)(ws + 1796096);
        uint32_t* xbits2 = (uint32_t*)(ws + 5007360);
        short* ci = (short*)(ws + 8218624);

        k_wprepP<<<2 * CC, 64, 0, stream>>>(w1, w2, wbits1, wbits2, alpha1, alpha2, adj1, adj2, s1sum);
        k_stats<<<NB * CC, 256, 0, stream>>>(x, s1sum, s1sq);
        k_bn1packP<<<NPIX / 64, 256, 0, stream>>>(x, s1sum, s1sq, g1, b1, xbits1, a1);
        k_box<<<NPIX / 256, 256, 0, stream>>>(a1, k1);
        k_convP<true><<<NB * 7 * 16, 448, 0, stream>>>(xbits1, wbits1, adj1, nullptr, nullptr, ci, nullptr, nullptr);
        k_stats2<<<NB * CC, 256, 0, stream>>>(ci, alpha1, k1, s2sum, s2sq);
        k_bn2packP<<<NPIX / 64, 256, 0, stream>>>(ci, alpha1, k1, s2sum, s2sq, g2, b2, xbits2, a2);
        k_convP<false><<<NB * 7 * 16, 448, 0, stream>>>(xbits2, wbits2, adj2, alpha2, a2, nullptr, x, out);
    }
}